// Round 14
// baseline (219.148 us; speedup 1.0000x reference)
//
#include <hip/hip_runtime.h>
#include <math.h>

#define BB 512
#define NN 1000
#define DD 128
#define HH 8
#define TILE 125   // 8 tiles of 125 rows

// ws layout: flag@0 (4B) | Afold@4096: [B][128][8] f32 (2 MB)
#define WS_AFOLD 4096

__device__ __forceinline__ bool mask_feasible(const void* mask, int flag, int idx) {
    if (flag == 1) return ((const int*)mask)[idx] != 0;
    if (flag == 2) return ((const float*)mask)[idx] != 0.0f;
    return ((const unsigned char*)mask)[idx] != 0;
}

__device__ __forceinline__ float rdl(float v, int srclane) {
    return __int_as_float(__builtin_amdgcn_readlane(__float_as_int(v), srclane));
}

// pack two f32 into one u32 of two bf16 (round-half-up, monotone-safe)
__device__ __forceinline__ unsigned pack2(float lo, float hi) {
    unsigned a = __float_as_uint(lo), b = __float_as_uint(hi);
    return ((a + 0x8000u) >> 16) | ((b + 0x8000u) & 0xffff0000u);
}
__device__ __forceinline__ float bflo(unsigned w) { return __uint_as_float(w << 16); }
__device__ __forceinline__ float bfhi(unsigned w) { return __uint_as_float(w & 0xffff0000u); }

// Detect action_mask storage dtype from its first 64 32-bit words.
__global__ void k0_detect(const unsigned int* __restrict__ m, int* __restrict__ flag) {
    int t = threadIdx.x;
    unsigned int w = m[t];
    unsigned long long bi = __ballot(w <= 1u);
    unsigned long long bf = __ballot(w == 0u || w == 0x3F800000u);
    if (t == 0) {
        int f = 0;
        if (bi == ~0ull) f = 1;
        else if (bf == ~0ull) f = 2;
        *flag = f;
    }
}

// Fused: mean over N -> q = mean@W_fixed + ctx@W_step -> Afold[c][h]
// (validated R4/R8/R12; single-arg launch_bounds only — R5: the 2nd arg acts
// as min-BLOCKS/CU, capped VGPR at 64, 518 MB scratch spill.)
__global__ __launch_bounds__(512) void kA_meanfold(
    const float* __restrict__ emb, const float* __restrict__ ctx,
    const float* __restrict__ W_fixed, const float* __restrict__ W_step,
    const float* __restrict__ W_node, float* __restrict__ Afold) {
    int b = blockIdx.x, t = threadIdx.x;
    __shared__ float4 red[512];
    __shared__ float mean_s[DD], cld[2 * DD], qlds[DD];
    int q4 = t & 31, j = t >> 5;
    const float4* e4 = (const float4*)(emb + (size_t)b * NN * DD);
    float4 acc = {0.f, 0.f, 0.f, 0.f};
    for (int n = j; n < NN; n += 16) {
        float4 v = e4[n * 32 + q4];
        acc.x += v.x; acc.y += v.y; acc.z += v.z; acc.w += v.w;
    }
    red[t] = acc;
    __syncthreads();
    for (int s = 8; s >= 1; s >>= 1) {
        if (j < s) {
            float4 o = red[t + s * 32], m = red[t];
            m.x += o.x; m.y += o.y; m.z += o.z; m.w += o.w;
            red[t] = m;
        }
        __syncthreads();
    }
    if (t < 32) {
        float4 m = red[t];
        const float inv = 1.0f / (float)NN;
        float4 r = {m.x * inv, m.y * inv, m.z * inv, m.w * inv};
        ((float4*)mean_s)[t] = r;
    }
    if (t < 256) cld[t] = ctx[b * 2 * DD + t];
    __syncthreads();
    if (t < 128) {
        float a = 0.f;
        for (int c = 0; c < DD; ++c)     a += mean_s[c] * W_fixed[c * DD + t];
        for (int c = 0; c < 2 * DD; ++c) a += cld[c] * W_step[c * DD + t];
        qlds[t] = a;
    }
    __syncthreads();
    if (t < 128) {
        const float* wrow = W_node + (size_t)t * 3 * DD;   // Wk cols [0,128)
        float* A2 = Afold + (size_t)b * 1024;
        for (int h = 0; h < HH; ++h) {
            float a = 0.f;
#pragma unroll
            for (int d0 = 0; d0 < 16; ++d0) a += wrow[h * 16 + d0] * qlds[h * 16 + d0];
            A2[t * 8 + h] = 0.25f * a;   // 1/sqrt(dk) folded
        }
    }
}

// R12's measured-best kB with ONE delta: the staged tile is bf16 (uint2 per
// 4 elems, 32 KB instead of 64 KB) -> static LDS ~36.9 KB -> 4 blocks/CU
// (16 waves/CU, 2x R12 occupancy). Same roles, TILE, barriers as R12.
__global__ __launch_bounds__(256) void kB_flash(
    const float* __restrict__ emb, const float* __restrict__ Afold,
    const void* __restrict__ mask, const int* __restrict__ flagp,
    const float* __restrict__ W_node, const float* __restrict__ W_out,
    float* __restrict__ out) {
    int b = blockIdx.x, t = threadIdx.x;
    int flag = *flagp;
    int lane = t & 63;
    int hq = (t >> 7) * 4;               // waves 0,1 -> h0..3 ; 2,3 -> h4..7
    int n = t & 127;                     // compat row (valid < TILE)
    int c4 = t & 31, jr = t >> 5;        // accumulate role (jr 0..7)

    __shared__ uint2 big[4096];          // 32 KB: bf16 tile [128][32]u2; then j-reduce/wemb/small
    __shared__ float cbuf[128][8];       // 4 KB: p values
    __shared__ float zl[HH];

    uint2* tile2 = big;

    // A lane-distributed: lane l holds A[l][hq+h'], A[64+l][hq+h']
    const float* Ab = Afold + (size_t)b * 1024;
    float a0l = Ab[lane * 8 + hq + 0], a1l = Ab[lane * 8 + hq + 1];
    float a2l = Ab[lane * 8 + hq + 2], a3l = Ab[lane * 8 + hq + 3];
    float a0h = Ab[(64 + lane) * 8 + hq + 0], a1h = Ab[(64 + lane) * 8 + hq + 1];
    float a2h = Ab[(64 + lane) * 8 + hq + 2], a3h = Ab[(64 + lane) * 8 + hq + 3];

    float4 wacc[8];
#pragma unroll
    for (int h = 0; h < HH; ++h) wacc[h] = make_float4(0.f, 0.f, 0.f, 0.f);
    float zrun = 0.f;                    // meaningful on t<8 only

    const float4* embB4 = (const float4*)(emb + (size_t)b * NN * DD);
    const int mbase = b * NN;

    for (int tile = 0; tile < 8; ++tile) {
        int n0 = tile * TILE;
        // ---- stage tile -> LDS as bf16 (coalesced global, swizzled write) ----
#pragma unroll
        for (int idx = 0; idx < 16; ++idx) {
            int i = t + idx * 256;
            if (i < TILE * 32) {
                int r = i >> 5, c = i & 31;
                float4 v = embB4[n0 * 32 + i];
                uint2 u;
                u.x = pack2(v.x, v.y);
                u.y = pack2(v.z, v.w);
                tile2[r * 32 + (c ^ (r & 31))] = u;
            }
        }
        __syncthreads();
        // ---- compat from LDS -> p = exp(compat) (no max-sub; validated R12) ----
        if (n < TILE) {
            int sw = n & 31;
            float4 s = make_float4(0.f, 0.f, 0.f, 0.f);
#pragma unroll 4
            for (int k = 0; k < 16; ++k) {          // cols 0..63
                uint2 u = tile2[n * 32 + (k ^ sw)];
                float e0 = bflo(u.x), e1 = bfhi(u.x), e2 = bflo(u.y), e3 = bfhi(u.y);
                int c = k * 4;
                s.x += e0 * rdl(a0l, c) + e1 * rdl(a0l, c + 1) + e2 * rdl(a0l, c + 2) + e3 * rdl(a0l, c + 3);
                s.y += e0 * rdl(a1l, c) + e1 * rdl(a1l, c + 1) + e2 * rdl(a1l, c + 2) + e3 * rdl(a1l, c + 3);
                s.z += e0 * rdl(a2l, c) + e1 * rdl(a2l, c + 1) + e2 * rdl(a2l, c + 2) + e3 * rdl(a2l, c + 3);
                s.w += e0 * rdl(a3l, c) + e1 * rdl(a3l, c + 1) + e2 * rdl(a3l, c + 2) + e3 * rdl(a3l, c + 3);
            }
#pragma unroll 4
            for (int k = 16; k < 32; ++k) {         // cols 64..127
                uint2 u = tile2[n * 32 + (k ^ sw)];
                float e0 = bflo(u.x), e1 = bfhi(u.x), e2 = bflo(u.y), e3 = bfhi(u.y);
                int c = k * 4 - 64;
                s.x += e0 * rdl(a0h, c) + e1 * rdl(a0h, c + 1) + e2 * rdl(a0h, c + 2) + e3 * rdl(a0h, c + 3);
                s.y += e0 * rdl(a1h, c) + e1 * rdl(a1h, c + 1) + e2 * rdl(a1h, c + 2) + e3 * rdl(a1h, c + 3);
                s.z += e0 * rdl(a2h, c) + e1 * rdl(a2h, c + 1) + e2 * rdl(a2h, c + 2) + e3 * rdl(a2h, c + 3);
                s.w += e0 * rdl(a3h, c) + e1 * rdl(a3h, c + 1) + e2 * rdl(a3h, c + 2) + e3 * rdl(a3h, c + 3);
            }
            bool feas = mask_feasible(mask, flag, mbase + n0 + n);
            float4 p = make_float4(0.f, 0.f, 0.f, 0.f);
            if (feas) {
                p.x = __expf(s.x); p.y = __expf(s.y);
                p.z = __expf(s.z); p.w = __expf(s.w);
            }
            *(float4*)&cbuf[n][hq] = p;
        }
        __syncthreads();
        // ---- z mini-reduce (wave 0; other waves proceed to accumulate) ----
        if (t < 64) {
            int h = t & 7, seg = t >> 3;
            float z = 0.f;
            for (int nn = seg; nn < TILE; nn += 8) z += cbuf[nn][h];
            z += __shfl_xor(z, 8);
            z += __shfl_xor(z, 16);
            z += __shfl_xor(z, 32);
            if (t < 8) zrun += z;
        }
        // ---- accumulate wemb from LDS tile (p broadcast from cbuf) ----
        for (int nn = jr; nn < TILE; nn += 8) {
            uint2 u = tile2[nn * 32 + (c4 ^ (nn & 31))];
            float e0 = bflo(u.x), e1 = bfhi(u.x), e2 = bflo(u.y), e3 = bfhi(u.y);
            float4 pA = *(const float4*)&cbuf[nn][0];
            float4 pB = *(const float4*)&cbuf[nn][4];
            wacc[0].x += pA.x * e0; wacc[0].y += pA.x * e1; wacc[0].z += pA.x * e2; wacc[0].w += pA.x * e3;
            wacc[1].x += pA.y * e0; wacc[1].y += pA.y * e1; wacc[1].z += pA.y * e2; wacc[1].w += pA.y * e3;
            wacc[2].x += pA.z * e0; wacc[2].y += pA.z * e1; wacc[2].z += pA.z * e2; wacc[2].w += pA.z * e3;
            wacc[3].x += pA.w * e0; wacc[3].y += pA.w * e1; wacc[3].z += pA.w * e2; wacc[3].w += pA.w * e3;
            wacc[4].x += pB.x * e0; wacc[4].y += pB.x * e1; wacc[4].z += pB.x * e2; wacc[4].w += pB.x * e3;
            wacc[5].x += pB.y * e0; wacc[5].y += pB.y * e1; wacc[5].z += pB.y * e2; wacc[5].w += pB.y * e3;
            wacc[6].x += pB.z * e0; wacc[6].y += pB.z * e1; wacc[6].z += pB.z * e2; wacc[6].w += pB.z * e3;
            wacc[7].x += pB.w * e0; wacc[7].y += pB.w * e1; wacc[7].z += pB.w * e2; wacc[7].w += pB.w * e3;
        }
        __syncthreads();   // tile2/cbuf dead before next stage
    }
    if (t < 8) zl[t] = zrun;
    // ---- j-reduce: write partials into big (32 KB), read+sum, then overwrite ----
    float4 wsum;
    {
        float4* red = (float4*)big;      // [8][32][8] float4 = 32 KB (fills big)
#pragma unroll
        for (int h = 0; h < HH; ++h) red[(jr * 32 + c4) * 8 + h] = wacc[h];
        __syncthreads();
        int cc = t >> 3, hh = t & 7;
        float4 s = make_float4(0.f, 0.f, 0.f, 0.f);
#pragma unroll
        for (int jj = 0; jj < 8; ++jj) {
            float4 v = red[(jj * 32 + cc) * 8 + hh];
            s.x += v.x; s.y += v.y; s.z += v.z; s.w += v.w;
        }
        float inv = 1.0f / zl[hh];
        wsum = make_float4(s.x * inv, s.y * inv, s.z * inv, s.w * inv);
    }
    __syncthreads();                     // all reads of red done before overwrite
    float* wemb_s = (float*)big;         // [8][128] f32 = 4 KB
    float* small  = (float*)big + 1024;  // hl/gl/g2 = 1.5 KB
    {
        int cc = t >> 3, hh = t & 7;
        *(float4*)&wemb_s[hh * 128 + cc * 4] = wsum;
    }
    __syncthreads();
    // ---- glimpse tail ----
    if (t < 128) {
        int h = t >> 4;
        float a = 0.f;
        for (int c = 0; c < DD; ++c) a += wemb_s[h * 128 + c] * W_node[(size_t)c * 384 + 128 + t];
        small[t] = a;                          // hl
    }
    __syncthreads();
    if (t < 128) {
        float g = 0.f;
        for (int k = 0; k < DD; ++k) g += small[k] * W_out[k * DD + t];
        small[128 + t] = g;                    // gl
    }
    __syncthreads();
    if (t < 128) {
        float a3 = 0.f;
        const float* wr = W_node + (size_t)t * 384 + 256;   // Wl row t
        for (int d = 0; d < DD; ++d) a3 += wr[d] * small[128 + d];
        small[256 + t] = a3;                   // g2
    }
    __syncthreads();
    // ---- logits tail (f32 emb from global; L2/L3-warm) ----
    const float4* g2v = (const float4*)&small[256];
    for (int r = t; r < NN; r += 256) {
        const float4* row = embB4 + (size_t)r * 32;
        float acc = 0.f;
#pragma unroll 8
        for (int k = 0; k < 32; ++k) {
            float4 e = row[k], g = g2v[k];
            acc += e.x * g.x + e.y * g.y + e.z * g.z + e.w * g.w;
        }
        bool feas = mask_feasible(mask, flag, mbase + r);
        out[(size_t)mbase + r] = feas ? (10.0f * tanhf(acc * 0.08838834764831845f)) : -1.0e30f;
    }
}

extern "C" void kernel_launch(void* const* d_in, const int* in_sizes, int n_in,
                              void* d_out, int out_size, void* d_ws, size_t ws_size,
                              hipStream_t stream) {
    (void)in_sizes; (void)n_in; (void)out_size; (void)ws_size;
    const float* emb     = (const float*)d_in[0];
    const float* ctx     = (const float*)d_in[1];
    const float* W_node  = (const float*)d_in[2];
    const float* W_fixed = (const float*)d_in[3];
    const float* W_step  = (const float*)d_in[4];
    const float* W_out   = (const float*)d_in[5];
    const void*  mask    = d_in[6];
    float* out = (float*)d_out;

    char* ws = (char*)d_ws;
    int*   flag  = (int*)(ws + 0);
    float* Afold = (float*)(ws + WS_AFOLD);

    k0_detect<<<1, 64, 0, stream>>>((const unsigned int*)mask, flag);
    kA_meanfold<<<BB, 512, 0, stream>>>(emb, ctx, W_fixed, W_step, W_node, Afold);
    kB_flash<<<BB, 256, 0, stream>>>(emb, Afold, mask, flag, W_node, W_out, out);
}